// Round 12
// baseline (207.156 us; speedup 1.0000x reference)
//
#include <hip/hip_runtime.h>

// MV_GCN on MI355X — round 13: single kernel, one block per graph.
// r11 = 49.6us k_fused + ~8us k_mlp + ~5us boundary, 157.6 total; ~100us of
// the timed region is fixed harness overhead (stable across r1/r7/r9/r11).
// This round fuses the MLP in WITHOUT cross-block communication: grid 256,
// for v in {0,1} over the r11-verified GCN body, feat kept in LDS, r8's
// (correct) MLP tail. Per-CU work unchanged; removes the second dispatch,
// its boundary, the featws HBM round-trip, and the 512-block 2-round tail.
// Secondary: AF_STR 117->120 (16B-aligned rows) so P3 reads are single
// f32x4 loads; scatter stays bank-spread (s is random).
// Spill tripwire: WRITE_SIZE must stay <2MB (r8's failure mode was scratch).

#define NB 256
#define NODES 116
#define FEAT 115
#define LENN 6670
#define SEG2 13456
#define HID 128
#define HC 512
#define AF_STR 120   // f32 A_hat row stride in words (480 B, 16B-aligned rows)

typedef float f32x4 __attribute__((ext_vector_type(4)));
typedef short short8 __attribute__((ext_vector_type(8)));
typedef __bf16 bf16x8 __attribute__((ext_vector_type(8)));

#define MFMA16(a, b, c) __builtin_amdgcn_mfma_f32_16x16x32_bf16( \
    __builtin_bit_cast(bf16x8, (a)), __builtin_bit_cast(bf16x8, (b)), (c), 0, 0, 0)

// LDS map (bytes): A_hi[0,32K) A_lo[32K,64K) B_hi[64K,96K) B_lo[96K,128K)
// f32 A_hat (stride 120, 55.7 KB) lives at B_hi pre-conversion.
// pmax[4][128] doubles as MLP ph[512]; sfeat[232]; red[8].
#define OFF_ALO 32768
#define OFF_BHI 65536
#define OFF_BLO 98304
#define OFF_PMAX 131072
#define OFF_DINV 133120
#define OFF_FEAT 133632
#define OFF_RED  134560
#define LDS_BYTES 134592

__device__ __forceinline__ unsigned short f2bf_s(float f) {
  return __builtin_bit_cast(unsigned short, (__bf16)f);
}
__device__ __forceinline__ float bf2f_s(unsigned short h) {
  return __builtin_bit_cast(float, (unsigned)h << 16);
}
// pack 4 f32 -> 4 bf16 hi + 4 bf16 lo (residual), as two uint2
__device__ __forceinline__ void cvt4(const float* v, uint2& hi, uint2& lo) {
  unsigned short h[4], l[4];
#pragma unroll
  for (int j = 0; j < 4; ++j) {
    h[j] = f2bf_s(v[j]);
    l[j] = f2bf_s(v[j] - bf2f_s(h[j]));
  }
  hi.x = (unsigned)h[0] | ((unsigned)h[1] << 16);
  hi.y = (unsigned)h[2] | ((unsigned)h[3] << 16);
  lo.x = (unsigned)l[0] | ((unsigned)l[1] << 16);
  lo.y = (unsigned)l[2] | ((unsigned)l[3] << 16);
}
__device__ __forceinline__ int kperm(int k) {  // frag k-order within 32-chunks
  return (k & ~31) | (k & 3) | (((k >> 2) & 3) << 3) | (((k >> 4) & 1) << 2);
}
__device__ __forceinline__ int kb64(int t) {   // byte base of k-quad 4t..4t+3
  return ((t & 3) << 4) | (((t >> 2) & 1) << 3) | ((t >> 3) << 6);
}
__device__ __forceinline__ int swzb(int row, int kbyte) {  // bank spread
  return row * 256 + (kbyte ^ ((row & 7) << 4));
}
__device__ __forceinline__ f32x4 splat4(float f) {
  f32x4 r = {f, f, f, f};
  return r;
}

__global__ __launch_bounds__(1024, 1) void k_all(
    const float* __restrict__ x, const int* __restrict__ ei,
    const float* __restrict__ ew,
    const float* __restrict__ W1, const float* __restrict__ b1,
    const float* __restrict__ W2, const float* __restrict__ b2,
    const float* __restrict__ W6, const float* __restrict__ b6,
    const float* __restrict__ W7, const float* __restrict__ b7,
    float* __restrict__ out)
{
  __shared__ __align__(16) char sm[LDS_BYTES];
  float* Afp   = (float*)(sm + OFF_BHI);      // f32 A_hat (stride 120)
  float* dinv  = (float*)(sm + OFF_DINV);
  float* pmaxp = (float*)(sm + OFF_PMAX);
  float* sfeat = (float*)(sm + OFF_FEAT);
  float* redp  = (float*)(sm + OFF_RED);
  const int g = blockIdx.x;
  const int tid = threadIdx.x;
  const int lane = tid & 63, w = tid >> 6;
  const int mg = w >> 2, ng = w & 3;
  const int rA0 = (mg << 5) + (lane & 15), rA1 = rA0 + 16;
  const int rB0 = (ng << 5) + (lane & 15), rB1 = rB0 + 16;
  const int kb = (lane >> 4) << 4;            // k-subgroup byte offset

  for (int v = 0; v < 2; ++v) {
    // ---- P0: zero f32 A region (116*120 = 13920 words = 3480 f32x4)
    {
      f32x4 z = splat4(0.f);
      f32x4* p = (f32x4*)(sm + OFF_BHI);
      for (int i = tid; i < 3480; i += 1024) p[i] = z;
    }
    __syncthreads();

    const int eoff = g * SEG2 + v * LENN;
    const int nbase = g * 232 + v * 116;

    // ---- P1: edge scatter A_raw[d][s] += w (random s -> uniform banks)
    {
      const int* __restrict__ srcp = ei + eoff;
      const int* __restrict__ dstp = ei + (size_t)NB * SEG2 + eoff;
      const float* __restrict__ wp = ew + eoff;
      for (int q = tid; q < (LENN / 2); q += 1024) {
        int2 s2 = ((const int2*)srcp)[q];
        int2 d2 = ((const int2*)dstp)[q];
        float2 w2 = ((const float2*)wp)[q];
        atomicAdd(&Afp[(d2.x - nbase) * AF_STR + (s2.x - nbase)], w2.x);
        atomicAdd(&Afp[(d2.y - nbase) * AF_STR + (s2.y - nbase)], w2.y);
      }
    }
    __syncthreads();

    // ---- P2: degree via row sums (4 threads/row, 29 cols each)
    if (tid < 4 * NODES) {
      const int r = tid >> 2, q = tid & 3;
      const float* row = Afp + r * AF_STR + q * 29;
      float s = 0.f;
#pragma unroll
      for (int j = 0; j < 29; ++j) s += row[j];
      s += __shfl_xor(s, 1, 64);
      s += __shfl_xor(s, 2, 64);
      if (q == 0) dinv[r] = rsqrtf(s + 1.0f);   // deg + 1 self-loop
    }
    __syncthreads();

    // ---- T14: issue X global loads now; latency hides under P3.
    float xr[4][4];
    {
      const float* __restrict__ xg = x + (size_t)nbase * FEAT;
#pragma unroll
      for (int i = 0; i < 4; ++i) {
        int u = tid + (i << 10);
        int t = u >> 7, c = u & 127;
#pragma unroll
        for (int j = 0; j < 4; ++j) {
          int s = 4 * t + j;
          xr[i][j] = (c < FEAT && s < NODES) ? xg[s * FEAT + c] : 0.f;
        }
      }
    }

    // ---- P3: normalize + convert f32 A (B region) -> bf16 hi/lo (A region).
    // Unit = (row, quad t): aligned f32x4 read (stride 120), b64 store sweeps
    // the full 256-B row across the wave. Quads t>=29 (cols>=116) -> zeros.
    for (int p = tid; p < NODES * 32; p += 1024) {
      const int row = p >> 5;
      const int t = p & 31;
      float tv[4] = {0.f, 0.f, 0.f, 0.f};
      if (t < 29) {
        const float dr = dinv[row];
        f32x4 q4 = *(const f32x4*)(Afp + row * AF_STR + (t << 2));
#pragma unroll
        for (int j = 0; j < 4; ++j) {
          const int cc = (t << 2) + j;        // <= 115
          float q = q4[j] * (dr * dinv[cc]);
          if (cc == row) q += dr * dr;
          tv[j] = q;
        }
      }
      uint2 hi, lo;
      cvt4(tv, hi, lo);
      const int byte = swzb(row, kb64(t));
      *(uint2*)(sm + byte) = hi;
      *(uint2*)(sm + OFF_ALO + byte) = lo;
    }
    __syncthreads();   // f32 A reads done; B region free for X^T

    // ---- P4: X^T bf16 hi/lo into B region (b64 packed; pads -> 0)
#pragma unroll
    for (int i = 0; i < 4; ++i) {
      int u = tid + (i << 10);
      int t = u >> 7, c = u & 127;
      uint2 hi, lo;
      cvt4(xr[i], hi, lo);
      int byte = swzb(c, kb64(t));
      *(uint2*)(sm + OFF_BHI + byte) = hi;
      *(uint2*)(sm + OFF_BLO + byte) = lo;
    }
    __syncthreads();

    // ---- T14: issue W global loads now; latency hides under P5's MFMAs.
    float wr[4][4];
    {
      const float* __restrict__ Wv = v ? W2 : W1;
#pragma unroll
      for (int i = 0; i < 4; ++i) {
        int u = tid + (i << 10);
        int t = u >> 7, c = u & 127;
#pragma unroll
        for (int j = 0; j < 4; ++j) {
          int k = 4 * t + j;
          wr[i][j] = (k < FEAT) ? Wv[(size_t)k * HID + c] : 0.f;
        }
      }
    }

    f32x4 acc00 = splat4(0.f), acc01 = splat4(0.f);
    f32x4 acc10 = splat4(0.f), acc11 = splat4(0.f);

    // ---- P5: M = A_hat @ X (bf16x3) — verified r7/r9/r11 core
#pragma unroll
    for (int kc = 0; kc < 4; ++kc) {
      const int ko = (kc << 6) + kb;
      short8 a0h = *(const short8*)(sm + swzb(rA0, ko));
      short8 a0l = *(const short8*)(sm + OFF_ALO + swzb(rA0, ko));
      short8 a1h = *(const short8*)(sm + swzb(rA1, ko));
      short8 a1l = *(const short8*)(sm + OFF_ALO + swzb(rA1, ko));
      short8 b0h = *(const short8*)(sm + OFF_BHI + swzb(rB0, ko));
      short8 b0l = *(const short8*)(sm + OFF_BLO + swzb(rB0, ko));
      short8 b1h = *(const short8*)(sm + OFF_BHI + swzb(rB1, ko));
      short8 b1l = *(const short8*)(sm + OFF_BLO + swzb(rB1, ko));
      acc00 = MFMA16(a0h, b0h, acc00); acc00 = MFMA16(a0l, b0h, acc00); acc00 = MFMA16(a0h, b0l, acc00);
      acc01 = MFMA16(a0h, b1h, acc01); acc01 = MFMA16(a0l, b1h, acc01); acc01 = MFMA16(a0h, b1l, acc01);
      acc10 = MFMA16(a1h, b0h, acc10); acc10 = MFMA16(a1l, b0h, acc10); acc10 = MFMA16(a1h, b0l, acc10);
      acc11 = MFMA16(a1h, b1h, acc11); acc11 = MFMA16(a1l, b1h, acc11); acc11 = MFMA16(a1h, b1l, acc11);
    }
    __syncthreads();   // all frag reads of A/B done

    // ---- P6: M -> A region (bf16 hi/lo); W^T -> B region (b64 packed)
    {
#pragma unroll
      for (int mt = 0; mt < 2; ++mt)
#pragma unroll
        for (int nt = 0; nt < 2; ++nt)
#pragma unroll
          for (int r2 = 0; r2 < 4; ++r2) {
            f32x4 a = (mt == 0) ? (nt == 0 ? acc00 : acc01)
                                : (nt == 0 ? acc10 : acc11);
            float f = a[r2];
            int row = (mg << 5) + (mt << 4) + ((lane >> 4) << 2) + r2;
            int col = (ng << 5) + (nt << 4) + (lane & 15);
            unsigned short hi = f2bf_s(f);
            unsigned short lo = f2bf_s(f - bf2f_s(hi));
            int byte = swzb(row, kperm(col) << 1);
            *(unsigned short*)(sm + byte) = hi;
            *(unsigned short*)(sm + OFF_ALO + byte) = lo;
          }
#pragma unroll
      for (int i = 0; i < 4; ++i) {
        int u = tid + (i << 10);
        int t = u >> 7, c = u & 127;
        uint2 hi, lo;
        cvt4(wr[i], hi, lo);
        int byte = swzb(c, kb64(t));
        *(uint2*)(sm + OFF_BHI + byte) = hi;
        *(uint2*)(sm + OFF_BLO + byte) = lo;
      }
    }
    __syncthreads();

    // ---- P7: out = M @ W + b (bf16x3), acc init = bias
    {
      const float* __restrict__ bv = v ? b2 : b1;
      float bb0 = bv[(ng << 5) + (lane & 15)];
      float bb1 = bv[(ng << 5) + 16 + (lane & 15)];
      acc00 = splat4(bb0); acc01 = splat4(bb1);
      acc10 = splat4(bb0); acc11 = splat4(bb1);
    }
#pragma unroll
    for (int kc = 0; kc < 4; ++kc) {
      const int ko = (kc << 6) + kb;
      short8 a0h = *(const short8*)(sm + swzb(rA0, ko));
      short8 a0l = *(const short8*)(sm + OFF_ALO + swzb(rA0, ko));
      short8 a1h = *(const short8*)(sm + swzb(rA1, ko));
      short8 a1l = *(const short8*)(sm + OFF_ALO + swzb(rA1, ko));
      short8 b0h = *(const short8*)(sm + OFF_BHI + swzb(rB0, ko));
      short8 b0l = *(const short8*)(sm + OFF_BLO + swzb(rB0, ko));
      short8 b1h = *(const short8*)(sm + OFF_BHI + swzb(rB1, ko));
      short8 b1l = *(const short8*)(sm + OFF_BLO + swzb(rB1, ko));
      acc00 = MFMA16(a0h, b0h, acc00); acc00 = MFMA16(a0l, b0h, acc00); acc00 = MFMA16(a0h, b0l, acc00);
      acc01 = MFMA16(a0h, b1h, acc01); acc01 = MFMA16(a0l, b1h, acc01); acc01 = MFMA16(a0h, b1l, acc01);
      acc10 = MFMA16(a1h, b0h, acc10); acc10 = MFMA16(a1l, b0h, acc10); acc10 = MFMA16(a1h, b0l, acc10);
      acc11 = MFMA16(a1h, b1h, acc11); acc11 = MFMA16(a1l, b1h, acc11); acc11 = MFMA16(a1h, b1l, acc11);
    }

    // ---- P8: channel max (over 128 hid cols) per node row -> sfeat (LDS)
#pragma unroll
    for (int mt = 0; mt < 2; ++mt)
#pragma unroll
      for (int r2 = 0; r2 < 4; ++r2) {
        f32x4 aN0 = (mt == 0) ? acc00 : acc10;
        f32x4 aN1 = (mt == 0) ? acc01 : acc11;
        float m = fmaxf(aN0[r2], aN1[r2]);
        m = fmaxf(m, __shfl_xor(m, 1, 64));
        m = fmaxf(m, __shfl_xor(m, 2, 64));
        m = fmaxf(m, __shfl_xor(m, 4, 64));
        m = fmaxf(m, __shfl_xor(m, 8, 64));
        if ((lane & 15) == 0) {
          int row = (mg << 5) + (mt << 4) + ((lane >> 4) << 2) + r2;
          pmaxp[(ng << 7) + row] = m;
        }
      }
    __syncthreads();
    if (tid < NODES) {
      float m = fmaxf(fmaxf(pmaxp[tid], pmaxp[128 + tid]),
                      fmaxf(pmaxp[256 + tid], pmaxp[384 + tid]));
      sfeat[2 * tid + v] = m;       // stack([x1,x2],1).reshape
    }
    __syncthreads();                // guards A/B reuse (v=1) and MLP reads
  }

  // ---- MLP: relu(feat@W6+b6)@W7+b7 (r8's verified tail; feat in LDS)
  {
    const int col = tid & 511, half = tid >> 9;
    const float* __restrict__ w6p = W6 + (size_t)(half * 116) * HC + col;
    const float* __restrict__ sfh = sfeat + half * 116;
    float p = 0.f;
#pragma unroll 4
    for (int k = 0; k < 116; ++k)
      p = fmaf(sfh[k], w6p[(size_t)k * HC], p);
    float* ph = pmaxp;              // pmax region reused (already consumed)
    if (half) ph[col] = p;
    __syncthreads();
    if (!half) {
      float a = b6[col] + p + ph[col];
      a = fmaxf(a, 0.f) * W7[col];
#pragma unroll
      for (int off = 32; off >= 1; off >>= 1) a += __shfl_xor(a, off, 64);
      if ((tid & 63) == 0) redp[tid >> 6] = a;
    }
    __syncthreads();
    if (tid == 0) {
      float t = b7[0];
#pragma unroll
      for (int i = 0; i < 8; ++i) t += redp[i];
      out[g] = t;
    }
  }
}

extern "C" void kernel_launch(void* const* d_in, const int* in_sizes, int n_in,
                              void* d_out, int out_size, void* d_ws, size_t ws_size,
                              hipStream_t stream)
{
  const float* x  = (const float*)d_in[0];
  const int*   ei = (const int*)d_in[1];
  const float* ew = (const float*)d_in[2];
  // d_in[3] = batch (unused by reference)
  const float* W1 = (const float*)d_in[4];
  const float* b1 = (const float*)d_in[5];
  const float* W2 = (const float*)d_in[6];
  const float* b2 = (const float*)d_in[7];
  const float* W6 = (const float*)d_in[8];
  const float* b6 = (const float*)d_in[9];
  const float* W7 = (const float*)d_in[10];
  const float* b7 = (const float*)d_in[11];
  float* out = (float*)d_out;

  hipLaunchKernelGGL(k_all, dim3(NB), dim3(1024), 0, stream,
                     x, ei, ew, W1, b1, W2, b2, W6, b6, W7, b7, out);
}

// Round 13
// 165.985 us; speedup vs baseline: 1.2480x; 1.2480x over previous
//
#include <hip/hip_runtime.h>

// MV_GCN on MI355X — round 14: r11 (best, 157.6us) + LDS-conflict fix only.
// r12 lesson: the ~95-100us gap is fixed harness cost, NOT per-dispatch
// (single-dispatch r12 showed the same gap); fusion spills (WRITE 76.8MB).
// So: exact r11 two-kernel structure, MFMA core untouched, two deltas:
//  1) t-sweep staging mapping (t=u&31, c=u>>5): half-wave has uniform LDS row
//     and sweeps all 32 8B-groups -> staging stores 8-way -> 2-way (free).
//     Global X/W loads become strided but are L2-resident + T14-prefetched.
//  2) AF_STR 117->120 + f32x4 P3 reads (aligned, dense 512B per half-wave,
//     conflict-free; ran correct inside r12).
// Predicted: conflicts 3.96M -> <=1.8M, k_fused 49.6 -> ~43-46us.

#define NB 256
#define NODES 116
#define FEAT 115
#define LENN 6670
#define SEG2 13456
#define HID 128
#define HC 512
#define AF_STR 120   // f32 A_hat row stride in words (480 B, 16B-aligned rows)

typedef float f32x4 __attribute__((ext_vector_type(4)));
typedef short short8 __attribute__((ext_vector_type(8)));
typedef __bf16 bf16x8 __attribute__((ext_vector_type(8)));

#define MFMA16(a, b, c) __builtin_amdgcn_mfma_f32_16x16x32_bf16( \
    __builtin_bit_cast(bf16x8, (a)), __builtin_bit_cast(bf16x8, (b)), (c), 0, 0, 0)

// LDS map (bytes): A_hi[0,32K) A_lo[32K,64K) B_hi[64K,96K) B_lo[96K,128K)
// f32 A_hat (stride 120, 55.7 KB) lives at B_hi pre-conversion.
#define OFF_ALO 32768
#define OFF_BHI 65536
#define OFF_BLO 98304
#define OFF_PMAX 131072
#define OFF_DINV 133120
#define LDS_BYTES 133632

__device__ __forceinline__ unsigned short f2bf_s(float f) {
  return __builtin_bit_cast(unsigned short, (__bf16)f);
}
__device__ __forceinline__ float bf2f_s(unsigned short h) {
  return __builtin_bit_cast(float, (unsigned)h << 16);
}
// pack 4 f32 -> 4 bf16 hi + 4 bf16 lo (residual), as two uint2
__device__ __forceinline__ void cvt4(const float* v, uint2& hi, uint2& lo) {
  unsigned short h[4], l[4];
#pragma unroll
  for (int j = 0; j < 4; ++j) {
    h[j] = f2bf_s(v[j]);
    l[j] = f2bf_s(v[j] - bf2f_s(h[j]));
  }
  hi.x = (unsigned)h[0] | ((unsigned)h[1] << 16);
  hi.y = (unsigned)h[2] | ((unsigned)h[3] << 16);
  lo.x = (unsigned)l[0] | ((unsigned)l[1] << 16);
  lo.y = (unsigned)l[2] | ((unsigned)l[3] << 16);
}
__device__ __forceinline__ int kperm(int k) {  // frag k-order within 32-chunks
  return (k & ~31) | (k & 3) | (((k >> 2) & 3) << 3) | (((k >> 4) & 1) << 2);
}
__device__ __forceinline__ int kb64(int t) {   // byte base of k-quad 4t..4t+3
  return ((t & 3) << 4) | (((t >> 2) & 1) << 3) | ((t >> 3) << 6);
}
__device__ __forceinline__ int swzb(int row, int kbyte) {  // bank spread
  return row * 256 + (kbyte ^ ((row & 7) << 4));
}
__device__ __forceinline__ f32x4 splat4(float f) {
  f32x4 r = {f, f, f, f};
  return r;
}

__global__ __launch_bounds__(1024, 1) void k_fused(
    const float* __restrict__ x, const int* __restrict__ ei,
    const float* __restrict__ ew,
    const float* __restrict__ W1, const float* __restrict__ b1,
    const float* __restrict__ W2, const float* __restrict__ b2,
    float* __restrict__ featws)
{
  __shared__ __align__(16) char sm[LDS_BYTES];
  float* Afp   = (float*)(sm + OFF_BHI);      // f32 A_hat (stride 120)
  float* dinv  = (float*)(sm + OFF_DINV);
  float* pmaxp = (float*)(sm + OFF_PMAX);
  const int bid = blockIdx.x;
  const int g = bid >> 1, v = bid & 1;
  const int tid = threadIdx.x;

  // ---- P0: zero f32 A region (116*120 = 13920 words = 3480 f32x4)
  {
    f32x4 z = splat4(0.f);
    f32x4* p = (f32x4*)(sm + OFF_BHI);
    for (int i = tid; i < 3480; i += 1024) p[i] = z;
  }
  __syncthreads();

  const int eoff = g * SEG2 + v * LENN;
  const int nbase = g * 232 + v * 116;

  // ---- P1: edge scatter A_raw[d][s] += w (random s -> uniform banks)
  {
    const int* __restrict__ srcp = ei + eoff;
    const int* __restrict__ dstp = ei + (size_t)NB * SEG2 + eoff;
    const float* __restrict__ wp = ew + eoff;
    for (int q = tid; q < (LENN / 2); q += 1024) {
      int2 s2 = ((const int2*)srcp)[q];
      int2 d2 = ((const int2*)dstp)[q];
      float2 w2 = ((const float2*)wp)[q];
      atomicAdd(&Afp[(d2.x - nbase) * AF_STR + (s2.x - nbase)], w2.x);
      atomicAdd(&Afp[(d2.y - nbase) * AF_STR + (s2.y - nbase)], w2.y);
    }
  }
  __syncthreads();

  // ---- P2: degree via row sums (4 threads/row, 29 cols each)
  if (tid < 4 * NODES) {
    const int r = tid >> 2, q = tid & 3;
    const float* row = Afp + r * AF_STR + q * 29;
    float s = 0.f;
#pragma unroll
    for (int j = 0; j < 29; ++j) s += row[j];
    s += __shfl_xor(s, 1, 64);
    s += __shfl_xor(s, 2, 64);
    if (q == 0) dinv[r] = rsqrtf(s + 1.0f);   // deg + 1 self-loop
  }
  __syncthreads();

  // ---- T14: issue X global loads now (t-sweep mapping); hides under P3.
  float xr[4][4];
  {
    const float* __restrict__ xg = x + (size_t)nbase * FEAT;
#pragma unroll
    for (int i = 0; i < 4; ++i) {
      int u = tid + (i << 10);
      int t = u & 31, c = u >> 5;            // c uniform per half-wave
#pragma unroll
      for (int j = 0; j < 4; ++j) {
        int s = 4 * t + j;
        xr[i][j] = (c < FEAT && s < NODES) ? xg[s * FEAT + c] : 0.f;
      }
    }
  }

  // ---- P3: normalize + convert f32 A (B region) -> bf16 hi/lo (A region).
  // Unit = (row, quad t): aligned f32x4 read (stride 120, dense 512B per
  // half-wave = conflict-free); b64 store sweeps the full 256-B row.
  for (int p = tid; p < NODES * 32; p += 1024) {
    const int row = p >> 5;
    const int t = p & 31;
    float tv[4] = {0.f, 0.f, 0.f, 0.f};
    if (t < 29) {
      const float dr = dinv[row];
      f32x4 q4 = *(const f32x4*)(Afp + row * AF_STR + (t << 2));
#pragma unroll
      for (int j = 0; j < 4; ++j) {
        const int cc = (t << 2) + j;        // <= 115
        float q = q4[j] * (dr * dinv[cc]);
        if (cc == row) q += dr * dr;
        tv[j] = q;
      }
    }
    uint2 hi, lo;
    cvt4(tv, hi, lo);
    const int byte = swzb(row, kb64(t));
    *(uint2*)(sm + byte) = hi;
    *(uint2*)(sm + OFF_ALO + byte) = lo;
  }
  __syncthreads();   // f32 A reads done; B region free for X^T

  // ---- P4: X^T bf16 hi/lo into B region (t-sweep: dense row writes, free)
#pragma unroll
  for (int i = 0; i < 4; ++i) {
    int u = tid + (i << 10);
    int t = u & 31, c = u >> 5;
    uint2 hi, lo;
    cvt4(xr[i], hi, lo);
    int byte = swzb(c, kb64(t));
    *(uint2*)(sm + OFF_BHI + byte) = hi;
    *(uint2*)(sm + OFF_BLO + byte) = lo;
  }
  __syncthreads();

  // ---- MFMA geometry (verified r7/r9/r11 core)
  const int lane = tid & 63, w = tid >> 6;
  const int mg = w >> 2, ng = w & 3;
  const int rA0 = (mg << 5) + (lane & 15), rA1 = rA0 + 16;
  const int rB0 = (ng << 5) + (lane & 15), rB1 = rB0 + 16;
  const int kb = (lane >> 4) << 4;            // k-subgroup byte offset

  // ---- T14: issue W global loads now (t-sweep); hides under P5's MFMAs.
  float wr[4][4];
  {
    const float* __restrict__ Wv = v ? W2 : W1;
#pragma unroll
    for (int i = 0; i < 4; ++i) {
      int u = tid + (i << 10);
      int t = u & 31, c = u >> 5;
#pragma unroll
      for (int j = 0; j < 4; ++j) {
        int k = 4 * t + j;
        wr[i][j] = (k < FEAT) ? Wv[(size_t)k * HID + c] : 0.f;
      }
    }
  }

  f32x4 acc00 = splat4(0.f), acc01 = splat4(0.f);
  f32x4 acc10 = splat4(0.f), acc11 = splat4(0.f);

  // ---- P5: M = A_hat @ X (bf16x3)
#pragma unroll
  for (int kc = 0; kc < 4; ++kc) {
    const int ko = (kc << 6) + kb;
    short8 a0h = *(const short8*)(sm + swzb(rA0, ko));
    short8 a0l = *(const short8*)(sm + OFF_ALO + swzb(rA0, ko));
    short8 a1h = *(const short8*)(sm + swzb(rA1, ko));
    short8 a1l = *(const short8*)(sm + OFF_ALO + swzb(rA1, ko));
    short8 b0h = *(const short8*)(sm + OFF_BHI + swzb(rB0, ko));
    short8 b0l = *(const short8*)(sm + OFF_BLO + swzb(rB0, ko));
    short8 b1h = *(const short8*)(sm + OFF_BHI + swzb(rB1, ko));
    short8 b1l = *(const short8*)(sm + OFF_BLO + swzb(rB1, ko));
    acc00 = MFMA16(a0h, b0h, acc00); acc00 = MFMA16(a0l, b0h, acc00); acc00 = MFMA16(a0h, b0l, acc00);
    acc01 = MFMA16(a0h, b1h, acc01); acc01 = MFMA16(a0l, b1h, acc01); acc01 = MFMA16(a0h, b1l, acc01);
    acc10 = MFMA16(a1h, b0h, acc10); acc10 = MFMA16(a1l, b0h, acc10); acc10 = MFMA16(a1h, b0l, acc10);
    acc11 = MFMA16(a1h, b1h, acc11); acc11 = MFMA16(a1l, b1h, acc11); acc11 = MFMA16(a1h, b1l, acc11);
  }
  __syncthreads();   // all frag reads of A/B done

  // ---- P6: M -> A region (bf16 hi/lo); W^T -> B region (t-sweep b64)
  {
#pragma unroll
    for (int mt = 0; mt < 2; ++mt)
#pragma unroll
      for (int nt = 0; nt < 2; ++nt)
#pragma unroll
        for (int r2 = 0; r2 < 4; ++r2) {
          f32x4 a = (mt == 0) ? (nt == 0 ? acc00 : acc01)
                              : (nt == 0 ? acc10 : acc11);
          float f = a[r2];
          int row = (mg << 5) + (mt << 4) + ((lane >> 4) << 2) + r2;
          int col = (ng << 5) + (nt << 4) + (lane & 15);
          unsigned short hi = f2bf_s(f);
          unsigned short lo = f2bf_s(f - bf2f_s(hi));
          int byte = swzb(row, kperm(col) << 1);
          *(unsigned short*)(sm + byte) = hi;
          *(unsigned short*)(sm + OFF_ALO + byte) = lo;
        }
#pragma unroll
    for (int i = 0; i < 4; ++i) {
      int u = tid + (i << 10);
      int t = u & 31, c = u >> 5;
      uint2 hi, lo;
      cvt4(wr[i], hi, lo);
      int byte = swzb(c, kb64(t));
      *(uint2*)(sm + OFF_BHI + byte) = hi;
      *(uint2*)(sm + OFF_BLO + byte) = lo;
    }
  }
  __syncthreads();

  // ---- P7: out = M @ W + b (bf16x3), acc init = bias
  {
    const float* __restrict__ bv = v ? b2 : b1;
    float bb0 = bv[(ng << 5) + (lane & 15)];
    float bb1 = bv[(ng << 5) + 16 + (lane & 15)];
    acc00 = splat4(bb0); acc01 = splat4(bb1);
    acc10 = splat4(bb0); acc11 = splat4(bb1);
  }
#pragma unroll
  for (int kc = 0; kc < 4; ++kc) {
    const int ko = (kc << 6) + kb;
    short8 a0h = *(const short8*)(sm + swzb(rA0, ko));
    short8 a0l = *(const short8*)(sm + OFF_ALO + swzb(rA0, ko));
    short8 a1h = *(const short8*)(sm + swzb(rA1, ko));
    short8 a1l = *(const short8*)(sm + OFF_ALO + swzb(rA1, ko));
    short8 b0h = *(const short8*)(sm + OFF_BHI + swzb(rB0, ko));
    short8 b0l = *(const short8*)(sm + OFF_BLO + swzb(rB0, ko));
    short8 b1h = *(const short8*)(sm + OFF_BHI + swzb(rB1, ko));
    short8 b1l = *(const short8*)(sm + OFF_BLO + swzb(rB1, ko));
    acc00 = MFMA16(a0h, b0h, acc00); acc00 = MFMA16(a0l, b0h, acc00); acc00 = MFMA16(a0h, b0l, acc00);
    acc01 = MFMA16(a0h, b1h, acc01); acc01 = MFMA16(a0l, b1h, acc01); acc01 = MFMA16(a0h, b1l, acc01);
    acc10 = MFMA16(a1h, b0h, acc10); acc10 = MFMA16(a1l, b0h, acc10); acc10 = MFMA16(a1h, b0l, acc10);
    acc11 = MFMA16(a1h, b1h, acc11); acc11 = MFMA16(a1l, b1h, acc11); acc11 = MFMA16(a1h, b1l, acc11);
  }

  // ---- P8: channel max (over 128 hid cols) per node row
#pragma unroll
  for (int mt = 0; mt < 2; ++mt)
#pragma unroll
    for (int r2 = 0; r2 < 4; ++r2) {
      f32x4 aN0 = (mt == 0) ? acc00 : acc10;
      f32x4 aN1 = (mt == 0) ? acc01 : acc11;
      float m = fmaxf(aN0[r2], aN1[r2]);
      m = fmaxf(m, __shfl_xor(m, 1, 64));
      m = fmaxf(m, __shfl_xor(m, 2, 64));
      m = fmaxf(m, __shfl_xor(m, 4, 64));
      m = fmaxf(m, __shfl_xor(m, 8, 64));
      if ((lane & 15) == 0) {
        int row = (mg << 5) + (mt << 4) + ((lane >> 4) << 2) + r2;
        pmaxp[(ng << 7) + row] = m;
      }
    }
  __syncthreads();
  if (tid < NODES) {
    float m = fmaxf(fmaxf(pmaxp[tid], pmaxp[128 + tid]),
                    fmaxf(pmaxp[256 + tid], pmaxp[384 + tid]));
    featws[g * 232 + 2 * tid + v] = m;   // stack([x1,x2],1).reshape
  }
}

// ---------------- K2: MLP  relu(feat@W6+b6)@W7+b7 ----------------
__global__ __launch_bounds__(1024) void k_mlp(
    const float* __restrict__ featws, const float* __restrict__ W6,
    const float* __restrict__ b6, const float* __restrict__ W7,
    const float* __restrict__ b7, float* __restrict__ out)
{
  __shared__ float sf[232];
  __shared__ float ph[512];
  __shared__ float red[8];
  const int g = blockIdx.x, tid = threadIdx.x;
  if (tid < 232) sf[tid] = featws[g * 232 + tid];
  __syncthreads();

  const int col = tid & 511, half = tid >> 9;
  const float* __restrict__ w6p = W6 + (size_t)(half * 116) * HC + col;
  const float* __restrict__ sfh = sf + half * 116;
  float p = 0.f;
#pragma unroll 4
  for (int k = 0; k < 116; ++k)
    p = fmaf(sfh[k], w6p[(size_t)k * HC], p);
  if (half) ph[col] = p;
  __syncthreads();

  if (!half) {
    float a = b6[col] + p + ph[col];
    a = fmaxf(a, 0.f) * W7[col];
#pragma unroll
    for (int off = 32; off >= 1; off >>= 1) a += __shfl_xor(a, off, 64);
    if ((tid & 63) == 0) red[tid >> 6] = a;
  }
  __syncthreads();
  if (tid == 0) {
    float t = b7[0];
#pragma unroll
    for (int i = 0; i < 8; ++i) t += red[i];
    out[g] = t;
  }
}

extern "C" void kernel_launch(void* const* d_in, const int* in_sizes, int n_in,
                              void* d_out, int out_size, void* d_ws, size_t ws_size,
                              hipStream_t stream)
{
  const float* x  = (const float*)d_in[0];
  const int*   ei = (const int*)d_in[1];
  const float* ew = (const float*)d_in[2];
  // d_in[3] = batch (unused by reference)
  const float* W1 = (const float*)d_in[4];
  const float* b1 = (const float*)d_in[5];
  const float* W2 = (const float*)d_in[6];
  const float* b2 = (const float*)d_in[7];
  const float* W6 = (const float*)d_in[8];
  const float* b6 = (const float*)d_in[9];
  const float* W7 = (const float*)d_in[10];
  const float* b7 = (const float*)d_in[11];

  float* featws = (float*)d_ws;                 // 256*232 f32 = 237 KB
  float* out    = (float*)d_out;

  hipLaunchKernelGGL(k_fused, dim3(2 * NB), dim3(1024), 0, stream,
                     x, ei, ew, W1, b1, W2, b2, featws);
  hipLaunchKernelGGL(k_mlp,   dim3(NB),     dim3(1024), 0, stream,
                     featws, W6, b6, W7, b7, out);
}

// Round 14
// 154.633 us; speedup vs baseline: 1.3397x; 1.0734x over previous
//
#include <hip/hip_runtime.h>

// MV_GCN on MI355X — round 15: r11 config (best k_fused 49.6us, total 157.6)
// + ONLY the P3 read fix from r13 (AF_STR 117->120, f32x4 reads).
// r13 lesson: t-sweep staging fixed 8-way LDS stores but UNCOALESCED the
// global X/W loads (lanes 1840B apart -> 64 lines/instr) — net −12us. The
// two deltas are separable; this round keeps r11's coalesced c-sweep staging
// and takes only the LDS-read-side win: P3's 4-way scalar reads become one
// dense conflict-free f32x4 (4x fewer LDS read instrs).
// Predicted: conflicts 3.96M -> ~3.3M, k_fused 49.6 -> ~47-49us.

#define NB 256
#define NODES 116
#define FEAT 115
#define LENN 6670
#define SEG2 13456
#define HID 128
#define HC 512
#define AF_STR 120   // f32 A_hat row stride in words (480 B, 16B-aligned rows)

typedef float f32x4 __attribute__((ext_vector_type(4)));
typedef short short8 __attribute__((ext_vector_type(8)));
typedef __bf16 bf16x8 __attribute__((ext_vector_type(8)));

#define MFMA16(a, b, c) __builtin_amdgcn_mfma_f32_16x16x32_bf16( \
    __builtin_bit_cast(bf16x8, (a)), __builtin_bit_cast(bf16x8, (b)), (c), 0, 0, 0)

// LDS map (bytes): A_hi[0,32K) A_lo[32K,64K) B_hi[64K,96K) B_lo[96K,128K)
// f32 A_hat (stride 120, 55.7 KB) lives at B_hi pre-conversion.
#define OFF_ALO 32768
#define OFF_BHI 65536
#define OFF_BLO 98304
#define OFF_PMAX 131072
#define OFF_DINV 133120
#define LDS_BYTES 133632

__device__ __forceinline__ unsigned short f2bf_s(float f) {
  return __builtin_bit_cast(unsigned short, (__bf16)f);
}
__device__ __forceinline__ float bf2f_s(unsigned short h) {
  return __builtin_bit_cast(float, (unsigned)h << 16);
}
// pack 4 f32 -> 4 bf16 hi + 4 bf16 lo (residual), as two uint2
__device__ __forceinline__ void cvt4(const float* v, uint2& hi, uint2& lo) {
  unsigned short h[4], l[4];
#pragma unroll
  for (int j = 0; j < 4; ++j) {
    h[j] = f2bf_s(v[j]);
    l[j] = f2bf_s(v[j] - bf2f_s(h[j]));
  }
  hi.x = (unsigned)h[0] | ((unsigned)h[1] << 16);
  hi.y = (unsigned)h[2] | ((unsigned)h[3] << 16);
  lo.x = (unsigned)l[0] | ((unsigned)l[1] << 16);
  lo.y = (unsigned)l[2] | ((unsigned)l[3] << 16);
}
__device__ __forceinline__ int kperm(int k) {  // frag k-order within 32-chunks
  return (k & ~31) | (k & 3) | (((k >> 2) & 3) << 3) | (((k >> 4) & 1) << 2);
}
__device__ __forceinline__ int kb64(int t) {   // byte base of k-quad 4t..4t+3
  return ((t & 3) << 4) | (((t >> 2) & 1) << 3) | ((t >> 3) << 6);
}
__device__ __forceinline__ int swzb(int row, int kbyte) {  // bank spread
  return row * 256 + (kbyte ^ ((row & 7) << 4));
}
__device__ __forceinline__ f32x4 splat4(float f) {
  f32x4 r = {f, f, f, f};
  return r;
}

__global__ __launch_bounds__(1024, 1) void k_fused(
    const float* __restrict__ x, const int* __restrict__ ei,
    const float* __restrict__ ew,
    const float* __restrict__ W1, const float* __restrict__ b1,
    const float* __restrict__ W2, const float* __restrict__ b2,
    float* __restrict__ featws)
{
  __shared__ __align__(16) char sm[LDS_BYTES];
  float* Afp   = (float*)(sm + OFF_BHI);      // f32 A_hat (stride 120)
  float* dinv  = (float*)(sm + OFF_DINV);
  float* pmaxp = (float*)(sm + OFF_PMAX);
  const int bid = blockIdx.x;
  const int g = bid >> 1, v = bid & 1;
  const int tid = threadIdx.x;

  // ---- P0: zero f32 A region (116*120 = 13920 words = 3480 f32x4)
  {
    f32x4 z = splat4(0.f);
    f32x4* p = (f32x4*)(sm + OFF_BHI);
    for (int i = tid; i < 3480; i += 1024) p[i] = z;
  }
  __syncthreads();

  const int eoff = g * SEG2 + v * LENN;
  const int nbase = g * 232 + v * 116;

  // ---- P1: edge scatter A_raw[d][s] += w (random s -> uniform banks)
  {
    const int* __restrict__ srcp = ei + eoff;
    const int* __restrict__ dstp = ei + (size_t)NB * SEG2 + eoff;
    const float* __restrict__ wp = ew + eoff;
    for (int q = tid; q < (LENN / 2); q += 1024) {
      int2 s2 = ((const int2*)srcp)[q];
      int2 d2 = ((const int2*)dstp)[q];
      float2 w2 = ((const float2*)wp)[q];
      atomicAdd(&Afp[(d2.x - nbase) * AF_STR + (s2.x - nbase)], w2.x);
      atomicAdd(&Afp[(d2.y - nbase) * AF_STR + (s2.y - nbase)], w2.y);
    }
  }
  __syncthreads();

  // ---- P2: degree via row sums (4 threads/row, 29 cols each)
  if (tid < 4 * NODES) {
    const int r = tid >> 2, q = tid & 3;
    const float* row = Afp + r * AF_STR + q * 29;
    float s = 0.f;
#pragma unroll
    for (int j = 0; j < 29; ++j) s += row[j];
    s += __shfl_xor(s, 1, 64);
    s += __shfl_xor(s, 2, 64);
    if (q == 0) dinv[r] = rsqrtf(s + 1.0f);   // deg + 1 self-loop
  }
  __syncthreads();

  // ---- T14: issue X global loads now (r11 c-sweep: coalesced); hides under P3.
  float xr[4][4];
  {
    const float* __restrict__ xg = x + (size_t)nbase * FEAT;
#pragma unroll
    for (int i = 0; i < 4; ++i) {
      int u = tid + (i << 10);
      int t = u >> 7, c = u & 127;           // lanes sweep c -> coalesced
#pragma unroll
      for (int j = 0; j < 4; ++j) {
        int s = 4 * t + j;
        xr[i][j] = (c < FEAT && s < NODES) ? xg[s * FEAT + c] : 0.f;
      }
    }
  }

  // ---- P3: normalize + convert f32 A (B region) -> bf16 hi/lo (A region).
  // Unit = (row, quad t): aligned f32x4 read (dense 512B/half-wave, conflict-
  // free); b64 store sweeps the full 256-B row. Quads t>=29 -> zeros.
  for (int p = tid; p < NODES * 32; p += 1024) {
    const int row = p >> 5;
    const int t = p & 31;
    float tv[4] = {0.f, 0.f, 0.f, 0.f};
    if (t < 29) {
      const float dr = dinv[row];
      f32x4 q4 = *(const f32x4*)(Afp + row * AF_STR + (t << 2));
#pragma unroll
      for (int j = 0; j < 4; ++j) {
        const int cc = (t << 2) + j;        // <= 115
        float q = q4[j] * (dr * dinv[cc]);
        if (cc == row) q += dr * dr;
        tv[j] = q;
      }
    }
    uint2 hi, lo;
    cvt4(tv, hi, lo);
    const int byte = swzb(row, kb64(t));
    *(uint2*)(sm + byte) = hi;
    *(uint2*)(sm + OFF_ALO + byte) = lo;
  }
  __syncthreads();   // f32 A reads done; B region free for X^T

  // ---- P4: X^T bf16 hi/lo into B region (r11 c-sweep, b64 packed)
#pragma unroll
  for (int i = 0; i < 4; ++i) {
    int u = tid + (i << 10);
    int t = u >> 7, c = u & 127;
    uint2 hi, lo;
    cvt4(xr[i], hi, lo);
    int byte = swzb(c, kb64(t));
    *(uint2*)(sm + OFF_BHI + byte) = hi;
    *(uint2*)(sm + OFF_BLO + byte) = lo;
  }
  __syncthreads();

  // ---- MFMA geometry (verified r7/r9/r11 core)
  const int lane = tid & 63, w = tid >> 6;
  const int mg = w >> 2, ng = w & 3;
  const int rA0 = (mg << 5) + (lane & 15), rA1 = rA0 + 16;
  const int rB0 = (ng << 5) + (lane & 15), rB1 = rB0 + 16;
  const int kb = (lane >> 4) << 4;            // k-subgroup byte offset

  // ---- T14: issue W global loads now (c-sweep); hides under P5's MFMAs.
  float wr[4][4];
  {
    const float* __restrict__ Wv = v ? W2 : W1;
#pragma unroll
    for (int i = 0; i < 4; ++i) {
      int u = tid + (i << 10);
      int t = u >> 7, c = u & 127;
#pragma unroll
      for (int j = 0; j < 4; ++j) {
        int k = 4 * t + j;
        wr[i][j] = (k < FEAT) ? Wv[(size_t)k * HID + c] : 0.f;
      }
    }
  }

  f32x4 acc00 = splat4(0.f), acc01 = splat4(0.f);
  f32x4 acc10 = splat4(0.f), acc11 = splat4(0.f);

  // ---- P5: M = A_hat @ X (bf16x3)
#pragma unroll
  for (int kc = 0; kc < 4; ++kc) {
    const int ko = (kc << 6) + kb;
    short8 a0h = *(const short8*)(sm + swzb(rA0, ko));
    short8 a0l = *(const short8*)(sm + OFF_ALO + swzb(rA0, ko));
    short8 a1h = *(const short8*)(sm + swzb(rA1, ko));
    short8 a1l = *(const short8*)(sm + OFF_ALO + swzb(rA1, ko));
    short8 b0h = *(const short8*)(sm + OFF_BHI + swzb(rB0, ko));
    short8 b0l = *(const short8*)(sm + OFF_BLO + swzb(rB0, ko));
    short8 b1h = *(const short8*)(sm + OFF_BHI + swzb(rB1, ko));
    short8 b1l = *(const short8*)(sm + OFF_BLO + swzb(rB1, ko));
    acc00 = MFMA16(a0h, b0h, acc00); acc00 = MFMA16(a0l, b0h, acc00); acc00 = MFMA16(a0h, b0l, acc00);
    acc01 = MFMA16(a0h, b1h, acc01); acc01 = MFMA16(a0l, b1h, acc01); acc01 = MFMA16(a0h, b1l, acc01);
    acc10 = MFMA16(a1h, b0h, acc10); acc10 = MFMA16(a1l, b0h, acc10); acc10 = MFMA16(a1h, b0l, acc10);
    acc11 = MFMA16(a1h, b1h, acc11); acc11 = MFMA16(a1l, b1h, acc11); acc11 = MFMA16(a1h, b1l, acc11);
  }
  __syncthreads();   // all frag reads of A/B done

  // ---- P6: M -> A region (bf16 hi/lo); W^T -> B region (c-sweep b64)
  {
#pragma unroll
    for (int mt = 0; mt < 2; ++mt)
#pragma unroll
      for (int nt = 0; nt < 2; ++nt)
#pragma unroll
        for (int r2 = 0; r2 < 4; ++r2) {
          f32x4 a = (mt == 0) ? (nt == 0 ? acc00 : acc01)
                              : (nt == 0 ? acc10 : acc11);
          float f = a[r2];
          int row = (mg << 5) + (mt << 4) + ((lane >> 4) << 2) + r2;
          int col = (ng << 5) + (nt << 4) + (lane & 15);
          unsigned short hi = f2bf_s(f);
          unsigned short lo = f2bf_s(f - bf2f_s(hi));
          int byte = swzb(row, kperm(col) << 1);
          *(unsigned short*)(sm + byte) = hi;
          *(unsigned short*)(sm + OFF_ALO + byte) = lo;
        }
#pragma unroll
    for (int i = 0; i < 4; ++i) {
      int u = tid + (i << 10);
      int t = u >> 7, c = u & 127;
      uint2 hi, lo;
      cvt4(wr[i], hi, lo);
      int byte = swzb(c, kb64(t));
      *(uint2*)(sm + OFF_BHI + byte) = hi;
      *(uint2*)(sm + OFF_BLO + byte) = lo;
    }
  }
  __syncthreads();

  // ---- P7: out = M @ W + b (bf16x3), acc init = bias
  {
    const float* __restrict__ bv = v ? b2 : b1;
    float bb0 = bv[(ng << 5) + (lane & 15)];
    float bb1 = bv[(ng << 5) + 16 + (lane & 15)];
    acc00 = splat4(bb0); acc01 = splat4(bb1);
    acc10 = splat4(bb0); acc11 = splat4(bb1);
  }
#pragma unroll
  for (int kc = 0; kc < 4; ++kc) {
    const int ko = (kc << 6) + kb;
    short8 a0h = *(const short8*)(sm + swzb(rA0, ko));
    short8 a0l = *(const short8*)(sm + OFF_ALO + swzb(rA0, ko));
    short8 a1h = *(const short8*)(sm + swzb(rA1, ko));
    short8 a1l = *(const short8*)(sm + OFF_ALO + swzb(rA1, ko));
    short8 b0h = *(const short8*)(sm + OFF_BHI + swzb(rB0, ko));
    short8 b0l = *(const short8*)(sm + OFF_BLO + swzb(rB0, ko));
    short8 b1h = *(const short8*)(sm + OFF_BHI + swzb(rB1, ko));
    short8 b1l = *(const short8*)(sm + OFF_BLO + swzb(rB1, ko));
    acc00 = MFMA16(a0h, b0h, acc00); acc00 = MFMA16(a0l, b0h, acc00); acc00 = MFMA16(a0h, b0l, acc00);
    acc01 = MFMA16(a0h, b1h, acc01); acc01 = MFMA16(a0l, b1h, acc01); acc01 = MFMA16(a0h, b1l, acc01);
    acc10 = MFMA16(a1h, b0h, acc10); acc10 = MFMA16(a1l, b0h, acc10); acc10 = MFMA16(a1h, b0l, acc10);
    acc11 = MFMA16(a1h, b1h, acc11); acc11 = MFMA16(a1l, b1h, acc11); acc11 = MFMA16(a1h, b1l, acc11);
  }

  // ---- P8: channel max (over 128 hid cols) per node row
#pragma unroll
  for (int mt = 0; mt < 2; ++mt)
#pragma unroll
    for (int r2 = 0; r2 < 4; ++r2) {
      f32x4 aN0 = (mt == 0) ? acc00 : acc10;
      f32x4 aN1 = (mt == 0) ? acc01 : acc11;
      float m = fmaxf(aN0[r2], aN1[r2]);
      m = fmaxf(m, __shfl_xor(m, 1, 64));
      m = fmaxf(m, __shfl_xor(m, 2, 64));
      m = fmaxf(m, __shfl_xor(m, 4, 64));
      m = fmaxf(m, __shfl_xor(m, 8, 64));
      if ((lane & 15) == 0) {
        int row = (mg << 5) + (mt << 4) + ((lane >> 4) << 2) + r2;
        pmaxp[(ng << 7) + row] = m;
      }
    }
  __syncthreads();
  if (tid < NODES) {
    float m = fmaxf(fmaxf(pmaxp[tid], pmaxp[128 + tid]),
                    fmaxf(pmaxp[256 + tid], pmaxp[384 + tid]));
    featws[g * 232 + 2 * tid + v] = m;   // stack([x1,x2],1).reshape
  }
}

// ---------------- K2: MLP  relu(feat@W6+b6)@W7+b7 ----------------
__global__ __launch_bounds__(1024) void k_mlp(
    const float* __restrict__ featws, const float* __restrict__ W6,
    const float* __restrict__ b6, const float* __restrict__ W7,
    const float* __restrict__ b7, float* __restrict__ out)
{
  __shared__ float sf[232];
  __shared__ float ph[512];
  __shared__ float red[8];
  const int g = blockIdx.x, tid = threadIdx.x;
  if (tid < 232) sf[tid] = featws[g * 232 + tid];
  __syncthreads();

  const int col = tid & 511, half = tid >> 9;
  const float* __restrict__ w6p = W6 + (size_t)(half * 116) * HC + col;
  const float* __restrict__ sfh = sf + half * 116;
  float p = 0.f;
#pragma unroll 4
  for (int k = 0; k < 116; ++k)
    p = fmaf(sfh[k], w6p[(size_t)k * HC], p);
  if (half) ph[col] = p;
  __syncthreads();

  if (!half) {
    float a = b6[col] + p + ph[col];
    a = fmaxf(a, 0.f) * W7[col];
#pragma unroll
    for (int off = 32; off >= 1; off >>= 1) a += __shfl_xor(a, off, 64);
    if ((tid & 63) == 0) red[tid >> 6] = a;
  }
  __syncthreads();
  if (tid == 0) {
    float t = b7[0];
#pragma unroll
    for (int i = 0; i < 8; ++i) t += red[i];
    out[g] = t;
  }
}

extern "C" void kernel_launch(void* const* d_in, const int* in_sizes, int n_in,
                              void* d_out, int out_size, void* d_ws, size_t ws_size,
                              hipStream_t stream)
{
  const float* x  = (const float*)d_in[0];
  const int*   ei = (const int*)d_in[1];
  const float* ew = (const float*)d_in[2];
  // d_in[3] = batch (unused by reference)
  const float* W1 = (const float*)d_in[4];
  const float* b1 = (const float*)d_in[5];
  const float* W2 = (const float*)d_in[6];
  const float* b2 = (const float*)d_in[7];
  const float* W6 = (const float*)d_in[8];
  const float* b6 = (const float*)d_in[9];
  const float* W7 = (const float*)d_in[10];
  const float* b7 = (const float*)d_in[11];

  float* featws = (float*)d_ws;                 // 256*232 f32 = 237 KB
  float* out    = (float*)d_out;

  hipLaunchKernelGGL(k_fused, dim3(2 * NB), dim3(1024), 0, stream,
                     x, ei, ew, W1, b1, W2, b2, featws);
  hipLaunchKernelGGL(k_mlp,   dim3(NB),     dim3(1024), 0, stream,
                     featws, W6, b6, W7, b7, out);
}